// Round 18
// baseline (1637.675 us; speedup 1.0000x reference)
//
#include <hip/hip_runtime.h>

typedef _Float16 h8 __attribute__((ext_vector_type(8)));
typedef __fp16 fp16x2 __attribute__((ext_vector_type(2)));
typedef float f4 __attribute__((ext_vector_type(4)));
typedef unsigned int u32;

#define HW 128
#define PLANE (HW*HW*16)
#define NPIX (32*HW*HW)
#define RSTRIDE 8448              // padded row stride: 132 cols * 4 gran * 16B

// split a,b (f32) into packed-f16 hi and lo words: hi=rtz(v), lo=rtz(v-hi)
static __device__ __forceinline__ void split2(float a, float b, u32& hi, u32& lo) {
  fp16x2 h = __builtin_amdgcn_cvt_pkrtz(a, b);
  fp16x2 l = __builtin_amdgcn_cvt_pkrtz(a - (float)h[0], b - (float)h[1]);
  union { fp16x2 v; u32 w; } uh, ul; uh.v = h; ul.v = l;
  hi = uh.w; lo = ul.w;
}

// ---------------- weight-fragment prep (hi/lo f16 split) ------------------
// W0F*: [kf(2)][nf(8)][lane(64)][j(8)]; W0eff[k][n], k=kf*32+(lane>>4)*8+j,
//   n=nf*16+(lane&15); W0eff = W0 (k<48), b0[n] at k==63 (bias slot), else 0.
// W1F*: [kf(4)][lane(64)][j(8)]; W1[k][c], c=lane&15, with the REDISTRIBUTION-
//   FREE k-order k = kf*32 + (j>>2)*16 + (lane>>4)*4 + (j&3): element j of the
//   GEMM2 B-frag is then exactly acc[2kf+(j>>2)][j&3] of the SAME lane.
// Buffers CONTIGUOUS: [0,16K)=W0hi | [16K,32K)=W0lo | [32K,36K)=W1hi |
// [36K,40K)=W1lo; k_mlp keeps W0hi in VGPRs and stages the last 24 KB in LDS.
__global__ __launch_bounds__(256) void k_wprep(const float* __restrict__ W0,
    const float* __restrict__ W1, const float* __restrict__ b0,
    _Float16* __restrict__ W0Fh, _Float16* __restrict__ W0Fl,
    _Float16* __restrict__ W1Fh, _Float16* __restrict__ W1Fl) {
  int t = blockIdx.x * 256 + threadIdx.x;
  if (t < 8192) {
    int i = t;
    int j = i & 7, lane = (i >> 3) & 63, nf = (i >> 9) & 7, kf = i >> 12;
    int gg = lane >> 4, k = kf * 32 + gg * 8 + j, n = nf * 16 + (lane & 15);
    float v = (k < 48) ? W0[k * 128 + n] : ((k == 63) ? b0[n] : 0.f);
    _Float16 hi = (_Float16)v;
    W0Fh[i] = hi; W0Fl[i] = (_Float16)(v - (float)hi);
  } else if (t < 10240) {
    int i = t - 8192;
    int j = i & 7, lane = (i >> 3) & 63, kf = i >> 9;
    int gg = lane >> 4, c = lane & 15;
    int k = kf * 32 + ((j >> 2) << 4) + gg * 4 + (j & 3);   // redistribution-free
    float v = W1[k * 16 + c];
    _Float16 hi = (_Float16)v;
    W1Fh[i] = hi; W1Fl[i] = (_Float16)(v - (float)hi);
  }
}

// read column cc (3 rows at local row.., 8 channels at (g&1)*8) from the
// ZERO-PADDED swizzled LDS x-tile. Padded col t = cc+1 (t=0 and t>=129 hold
// zeros; OOB rows staged as zeros) -> NO masks/clamps/selects. Granules
// tg, tg+1 (tg even); swizzle p = tg^((tg>>5)&7) XORs bits 0..2 only, so
// the pair partner is at p^1 (r12 lesson). Rows via +0/+RSTRIDE/+2*RSTRIDE.
#define LDQ(cc, q) do {                                              \
    int _tg = ((cc) + 1) * 4 + chq;                                  \
    int _p = _tg ^ ((_tg >> 5) & 7);                                 \
    int _o0 = _p * 16, _o1 = (_p ^ 1) * 16;                          \
    q[0][0] = *(const f4*)(xsw + _o0);                               \
    q[0][1] = *(const f4*)(xsw + _o1);                               \
    q[1][0] = *(const f4*)(xsw + RSTRIDE + _o0);                     \
    q[1][1] = *(const f4*)(xsw + RSTRIDE + _o1);                     \
    q[2][0] = *(const f4*)(xsw + 2 * RSTRIDE + _o0);                 \
    q[2][1] = *(const f4*)(xsw + 2 * RSTRIDE + _o1);                 \
  } while (0)

// ---------------- fused MLP: features -> split-f16 MFMA x2 -> planar dx ---
// Block (b, cd, half) covers mlp rows hp in [8cd+4*half, +4), 512 THREADS =
// 8 waves: wave wv owns a HALF-ROW (row wv>>1, chunks u in [4*(wv&1),+4)).
// Same per-block work & LDS as r16 (75264B, 2 blocks/CU) but 2x waves in
// flight: 16 waves/CU = 4 waves/SIMD (VGPR 4x124=496<=512 exactly). r16's
// pipe audit showed no pipe >50% busy at 8 waves/CU -> latency-bound; with
// the r13 LDS-staged short chain, doubling waves raises issue density
// (r11's grid-double failed because the chain was then global-latency-
// dominated). Per-lane code identical to r16 (weights back in LDS; r17's
// weights-from-global regressed: x-tile staging thrashed L1).
__global__ __launch_bounds__(512, 4) void k_mlp(const float* __restrict__ x,
    float* __restrict__ dxp, const _Float16* __restrict__ W0Fh,
    const _Float16* __restrict__ W0Fl) {
  __shared__ __align__(16) char smem[75264];  // 50688 x-tile | 24576 weights
  const int tid = threadIdx.x;
  const int lane = tid & 63, wv = tid >> 6;   // wv 0..7
  const int g = lane >> 4, m = lane & 15;
  const int bid = blockIdx.x;
  const int b = bid >> 5, cd = (bid >> 1) & 15, half = bid & 1;
  const int hp0 = cd * 8 + half * 4;
  const float* xb = x + (size_t)b * PLANE;
  float* dpl = dxp + (size_t)(b * 16 + cd) * (HW * HW);

  // ---- stage 6 x rows (hp0-1..hp0+4) zero-padded + swizzled ----
  {
    f4 st[7];
    const f4 zf = {0.f, 0.f, 0.f, 0.f};
    #pragma unroll
    for (int k = 0; k < 7; ++k) {
      int i = tid + k * 512;                 // 0..3583, valid < 3168
      int row = i / 528, tg = i - row * 528;
      int tc = tg >> 2;                      // padded col 0..131
      int grow = hp0 - 1 + row;
      bool v = (i < 3168) && ((unsigned)grow < 128u) &&
               (tc >= 1) && (tc <= 128);
      st[k] = v ? *(const f4*)((const char*)(xb + (size_t)grow * 2048)
                               + (tc - 1) * 64 + (tg & 3) * 16)
                : zf;
    }
    #pragma unroll
    for (int k = 0; k < 7; ++k) {
      int i = tid + k * 512;
      if (i < 3168) {
        int row = i / 528, tg = i - row * 528;
        int p = tg ^ ((tg >> 5) & 7);
        *(f4*)(smem + row * RSTRIDE + p * 16) = st[k];
      }
    }
    // weights: W0lo|W1hi|W1lo (24 KB contiguous at W0Fl) -> smem+50688
    float4* dst = (float4*)(smem + 50688);
    const float4* src = (const float4*)W0Fl;
    for (int i = tid; i < 1536; i += 512) dst[i] = src[i];
  }
  __syncthreads();

  // persistent W0-hi fragments in VGPRs (64 regs)
  h8 w0h[2][8];
  #pragma unroll
  for (int kf = 0; kf < 2; ++kf)
    #pragma unroll
    for (int nf = 0; nf < 8; ++nf)
      w0h[kf][nf] = *(const h8*)(W0Fh + ((kf * 8 + nf) * 64 + lane) * 8);

  const f4 zero4 = {0.f, 0.f, 0.f, 0.f};
  const int chq = (g & 1) * 2;              // granule sub-offset for this g
  const bool lowg = (g < 2);

  const int hp = hp0 + (wv >> 1);
  const int u0 = (wv & 1) * 4;              // half-row chunk range
  const char* xsw = smem + (wv >> 1) * RSTRIDE;  // local row = global hp-1
  float* dbase = dpl + (size_t)(hp & 7) * 16 + m + (size_t)g * 4 * 128;

  for (int uu = 0; uu < 4; ++uu) {
    const int u = u0 + uu;
    const int wp = u + 8 * m;
    // ---- read 3x3-neighborhood columns from LDS (unconditional) ----
    f4 qA[3][2], qB[3][2], qC[3][2];
    LDQ(wp - 1, qA); LDQ(wp, qB); LDQ(wp + 1, qC);

    // ---- features: center / sobel-dh / sobel-dw for 8 channels ----
    f4 cen0 = qB[1][0], cen1 = qB[1][1];
    f4 sH0 = ((qA[2][0] - qA[0][0]) + 2.f * (qB[2][0] - qB[0][0])
            + (qC[2][0] - qC[0][0])) * 0.125f;
    f4 sH1 = ((qA[2][1] - qA[0][1]) + 2.f * (qB[2][1] - qB[0][1])
            + (qC[2][1] - qC[0][1])) * 0.125f;
    f4 vA0 = qA[0][0] + 2.f * qA[1][0] + qA[2][0];
    f4 vA1 = qA[0][1] + 2.f * qA[1][1] + qA[2][1];
    f4 vC0 = qC[0][0] + 2.f * qC[1][0] + qC[2][0];
    f4 vC1 = qC[0][1] + 2.f * qC[1][1] + qC[2][1];
    f4 sW0 = (vC0 - vA0) * 0.125f;
    f4 sW1 = (vC1 - vA1) * 0.125f;

    f4 f0lo = lowg ? cen0 : sH0, f0hi = lowg ? cen1 : sH1;
    f4 f1lo = lowg ? sW0 : zero4, f1hi = lowg ? sW1 : zero4;

    // ---- split features to hi/lo f16 pairs ----
    union { h8 v; u32 u[4]; } b0h, b0l, b1h, b1l;
    #pragma unroll
    for (int q = 0; q < 4; ++q) {
      float a0 = (q < 2) ? f0lo[2 * q]     : f0hi[2 * q - 4];
      float a1 = (q < 2) ? f0lo[2 * q + 1] : f0hi[2 * q - 3];
      split2(a0, a1, b0h.u[q], b0l.u[q]);
      float c0 = (q < 2) ? f1lo[2 * q]     : f1hi[2 * q - 4];
      float c1 = (q < 2) ? f1lo[2 * q + 1] : f1hi[2 * q - 3];
      split2(c0, c1, b1h.u[q], b1l.u[q]);
    }
    if (g == 3) {                        // bias slot: B[k=63] = 1.0 exactly
      b1h.u[3] = (b1h.u[3] & 0xFFFFu) | 0x3C000000u;
      b1l.u[3] =  b1l.u[3] & 0xFFFFu;
    }

    // ---- fused GEMM1 -> relu/split -> GEMM2, all in-lane; split chains ----
    f4 q0 = zero4, q1 = zero4, q2 = zero4, q3 = zero4;  // GEMM2 per-p chains
    #pragma unroll
    for (int p = 0; p < 4; ++p) {
      f4 aAh = zero4, aAl = zero4, aBh = zero4, aBl = zero4;
      {
        const int nf = 2 * p;
        h8 l0 = *(const h8*)(smem + 50688 + nf * 1024 + lane * 16);  // lo kf0
        h8 l1 = *(const h8*)(smem + 58880 + nf * 1024 + lane * 16);  // lo kf1
        aAh = __builtin_amdgcn_mfma_f32_16x16x32_f16(w0h[0][nf], b0h.v, aAh, 0, 0, 0);
        aAh = __builtin_amdgcn_mfma_f32_16x16x32_f16(w0h[1][nf], b1h.v, aAh, 0, 0, 0);
        aAh = __builtin_amdgcn_mfma_f32_16x16x32_f16(w0h[0][nf], b0l.v, aAh, 0, 0, 0);
        aAh = __builtin_amdgcn_mfma_f32_16x16x32_f16(w0h[1][nf], b1l.v, aAh, 0, 0, 0);
        aAl = __builtin_amdgcn_mfma_f32_16x16x32_f16(l0, b0h.v, aAl, 0, 0, 0);
        aAl = __builtin_amdgcn_mfma_f32_16x16x32_f16(l1, b1h.v, aAl, 0, 0, 0);
      }
      {
        const int nf = 2 * p + 1;
        h8 l0 = *(const h8*)(smem + 50688 + nf * 1024 + lane * 16);
        h8 l1 = *(const h8*)(smem + 58880 + nf * 1024 + lane * 16);
        aBh = __builtin_amdgcn_mfma_f32_16x16x32_f16(w0h[0][nf], b0h.v, aBh, 0, 0, 0);
        aBh = __builtin_amdgcn_mfma_f32_16x16x32_f16(w0h[1][nf], b1h.v, aBh, 0, 0, 0);
        aBh = __builtin_amdgcn_mfma_f32_16x16x32_f16(w0h[0][nf], b0l.v, aBh, 0, 0, 0);
        aBh = __builtin_amdgcn_mfma_f32_16x16x32_f16(w0h[1][nf], b1l.v, aBh, 0, 0, 0);
        aBl = __builtin_amdgcn_mfma_f32_16x16x32_f16(l0, b0h.v, aBl, 0, 0, 0);
        aBl = __builtin_amdgcn_mfma_f32_16x16x32_f16(l1, b1h.v, aBl, 0, 0, 0);
      }
      f4 aA = aAh + aAl;
      f4 aB = aBh + aBl;
      // relu + hi/lo split, element j of B-frag = acc[2p+(j>>2)][j&3]
      union { h8 v; u32 u[4]; } hh, hl;
      split2(fmaxf(aA[0], 0.f), fmaxf(aA[1], 0.f), hh.u[0], hl.u[0]);
      split2(fmaxf(aA[2], 0.f), fmaxf(aA[3], 0.f), hh.u[1], hl.u[1]);
      split2(fmaxf(aB[0], 0.f), fmaxf(aB[1], 0.f), hh.u[2], hl.u[2]);
      split2(fmaxf(aB[2], 0.f), fmaxf(aB[3], 0.f), hh.u[3], hl.u[3]);
      h8 w1hp = *(const h8*)(smem + 67072 + p * 1024 + lane * 16);
      h8 w1lp = *(const h8*)(smem + 71168 + p * 1024 + lane * 16);
      f4 qp = (p == 0) ? q0 : (p == 1) ? q1 : (p == 2) ? q2 : q3;
      qp = __builtin_amdgcn_mfma_f32_16x16x32_f16(w1hp, hh.v, qp, 0, 0, 0);
      qp = __builtin_amdgcn_mfma_f32_16x16x32_f16(w1hp, hl.v, qp, 0, 0, 0);
      qp = __builtin_amdgcn_mfma_f32_16x16x32_f16(w1lp, hh.v, qp, 0, 0, 0);
      if (p == 0) q0 = qp; else if (p == 1) q1 = qp;
      else if (p == 2) q2 = qp; else q3 = qp;
    }
    f4 acc2 = (q0 + q1) + (q2 + q3);

    // ---- store dx plane: lane (g,m) holds cq=4g+r for pixel m ----
    #pragma unroll
    for (int r = 0; r < 4; ++r)
      dbase[(size_t)(u * 16 + r) * 128] = acc2[r];
  }
}

// ---------------- fused residual add + alive masking ----------------------
__global__ __launch_bounds__(256) void k_addlife(const float* __restrict__ xo,
    const float* __restrict__ dxp, float* __restrict__ xn) {
  int p = blockIdx.x * 256 + threadIdx.x;
  int b = p >> 14, rem = p & 16383;
  int h = rem >> 7, w = rem & 127;
  const float* xop = xo + (size_t)p * 16;
  const float* dplane = dxp + (size_t)b * 16 * 16384;
  f4 xv[4];
  #pragma unroll
  for (int i = 0; i < 4; ++i) xv[i] = *(const f4*)(xop + i * 4);
  float dxv[16];
  #pragma unroll
  for (int c = 0; c < 16; ++c) dxv[c] = dplane[c * 16384 + rem];
  f4 nv[4];
  #pragma unroll
  for (int i = 0; i < 4; ++i) {
    nv[i][0] = xv[i][0] + dxv[i * 4 + 0];
    nv[i][1] = xv[i][1] + dxv[i * 4 + 1];
    nv[i][2] = xv[i][2] + dxv[i * 4 + 2];
    nv[i][3] = xv[i][3] + dxv[i * 4 + 3];
  }
  float pre = -1e30f, post = -1e30f;
  const float* xb3 = xo + (size_t)b * 16384 * 16 + 3;
  const float* d3p = dplane + 3 * 16384;
  #pragma unroll
  for (int dh = -1; dh <= 1; ++dh)
    #pragma unroll
    for (int dw = -1; dw <= 1; ++dw) {
      int hh = h + dh, ww = w + dw;
      bool v = ((unsigned)hh < 128u) && ((unsigned)ww < 128u);
      int rp = hh * 128 + ww;
      float x3 = v ? xb3[(size_t)rp * 16] : -1e30f;
      float d3 = v ? d3p[rp] : 0.f;
      pre = fmaxf(pre, x3);
      post = fmaxf(post, v ? (x3 + d3) : -1e30f);
    }
  bool life = (pre > 0.1f) && (post > 0.1f);
  float* out = xn + (size_t)p * 16;
  f4 z = {0.f, 0.f, 0.f, 0.f};
  #pragma unroll
  for (int i = 0; i < 4; ++i) *(f4*)(out + i * 4) = life ? nv[i] : z;
}

extern "C" void kernel_launch(void* const* d_in, const int* in_sizes, int n_in,
                              void* d_out, int out_size, void* d_ws, size_t ws_size,
                              hipStream_t stream) {
  const float* x0 = (const float*)d_in[0];
  const float* W0 = (const float*)d_in[1];
  const float* b0 = (const float*)d_in[2];
  const float* W1 = (const float*)d_in[3];

  float*    A    = (float*)d_ws;                                  // 32 MB x ping
  float*    dxp  = (float*)((char*)d_ws + ((size_t)32 << 20));    // 32 MB dx
  _Float16* W0Fh = (_Float16*)((char*)d_ws + ((size_t)64 << 20)); // 16 KB
  _Float16* W0Fl = W0Fh + 8192;   // 16 KB  (W0Fh|W0Fl|W1Fh|W1Fl contig 40 KB)
  _Float16* W1Fh = W0Fl + 8192;   // 4 KB
  _Float16* W1Fl = W1Fh + 2048;   // 4 KB
  float*    Bo   = (float*)d_out;

  k_wprep<<<40, 256, 0, stream>>>(W0, W1, b0, W0Fh, W0Fl, W1Fh, W1Fl);

  const float* xcur = x0;
  for (int s = 1; s <= 8; ++s) {
    k_mlp<<<1024, 512, 0, stream>>>(xcur, dxp, W0Fh, W0Fl);
    float* xnext = (s & 1) ? A : Bo;        // step 8 lands in d_out
    k_addlife<<<2048, 256, 0, stream>>>(xcur, dxp, xnext);
    xcur = xnext;
  }
}

// Round 19
// 519.967 us; speedup vs baseline: 3.1496x; 3.1496x over previous
//
#include <hip/hip_runtime.h>

typedef _Float16 h8 __attribute__((ext_vector_type(8)));
typedef __fp16 fp16x2 __attribute__((ext_vector_type(2)));
typedef float f4 __attribute__((ext_vector_type(4)));
typedef unsigned int u32;

#define HW 128
#define PLANE (HW*HW*16)
#define NPIX (32*HW*HW)
#define RSTRIDE 8448              // padded row stride: 132 cols * 4 gran * 16B

// split a,b (f32) into packed-f16 hi and lo words: hi=rtz(v), lo=rtz(v-hi)
static __device__ __forceinline__ void split2(float a, float b, u32& hi, u32& lo) {
  fp16x2 h = __builtin_amdgcn_cvt_pkrtz(a, b);
  fp16x2 l = __builtin_amdgcn_cvt_pkrtz(a - (float)h[0], b - (float)h[1]);
  union { fp16x2 v; u32 w; } uh, ul; uh.v = h; ul.v = l;
  hi = uh.w; lo = ul.w;
}

// ---------------- weight-fragment prep (hi/lo f16 split) ------------------
// W0F*: [kf(2)][nf(8)][lane(64)][j(8)]; W0eff[k][n], k=kf*32+(lane>>4)*8+j,
//   n=nf*16+(lane&15); W0eff = W0 (k<48), b0[n] at k==63 (bias slot), else 0.
// W1F*: [kf(4)][lane(64)][j(8)]; W1[k][c], c=lane&15, with the REDISTRIBUTION-
//   FREE k-order k = kf*32 + (j>>2)*16 + (lane>>4)*4 + (j&3): element j of the
//   GEMM2 B-frag is then exactly acc[2kf+(j>>2)][j&3] of the SAME lane.
// Buffers CONTIGUOUS: [0,16K)=W0hi | [16K,32K)=W0lo | [32K,36K)=W1hi |
// [36K,40K)=W1lo; k_mlp keeps W0hi in VGPRs and stages the last 24 KB in LDS.
__global__ __launch_bounds__(256) void k_wprep(const float* __restrict__ W0,
    const float* __restrict__ W1, const float* __restrict__ b0,
    _Float16* __restrict__ W0Fh, _Float16* __restrict__ W0Fl,
    _Float16* __restrict__ W1Fh, _Float16* __restrict__ W1Fl) {
  int t = blockIdx.x * 256 + threadIdx.x;
  if (t < 8192) {
    int i = t;
    int j = i & 7, lane = (i >> 3) & 63, nf = (i >> 9) & 7, kf = i >> 12;
    int gg = lane >> 4, k = kf * 32 + gg * 8 + j, n = nf * 16 + (lane & 15);
    float v = (k < 48) ? W0[k * 128 + n] : ((k == 63) ? b0[n] : 0.f);
    _Float16 hi = (_Float16)v;
    W0Fh[i] = hi; W0Fl[i] = (_Float16)(v - (float)hi);
  } else if (t < 10240) {
    int i = t - 8192;
    int j = i & 7, lane = (i >> 3) & 63, kf = i >> 9;
    int gg = lane >> 4, c = lane & 15;
    int k = kf * 32 + ((j >> 2) << 4) + gg * 4 + (j & 3);   // redistribution-free
    float v = W1[k * 16 + c];
    _Float16 hi = (_Float16)v;
    W1Fh[i] = hi; W1Fl[i] = (_Float16)(v - (float)hi);
  }
}

// read column cc (3 rows at local row.., 8 channels at (g&1)*8) from the
// ZERO-PADDED swizzled LDS x-tile. Padded col t = cc+1 (t=0 and t>=129 hold
// zeros; OOB rows staged as zeros) -> NO masks/clamps/selects. Granules
// tg, tg+1 (tg even); swizzle p = tg^((tg>>5)&7) XORs bits 0..2 only, so
// the pair partner is at p^1 (r12 lesson). Rows via +0/+RSTRIDE/+2*RSTRIDE.
#define LDQ(cc, q) do {                                              \
    int _tg = ((cc) + 1) * 4 + chq;                                  \
    int _p = _tg ^ ((_tg >> 5) & 7);                                 \
    int _o0 = _p * 16, _o1 = (_p ^ 1) * 16;                          \
    q[0][0] = *(const f4*)(xsw + _o0);                               \
    q[0][1] = *(const f4*)(xsw + _o1);                               \
    q[1][0] = *(const f4*)(xsw + RSTRIDE + _o0);                     \
    q[1][1] = *(const f4*)(xsw + RSTRIDE + _o1);                     \
    q[2][0] = *(const f4*)(xsw + 2 * RSTRIDE + _o0);                 \
    q[2][1] = *(const f4*)(xsw + 2 * RSTRIDE + _o1);                 \
  } while (0)

// ---------------- fused MLP: features -> split-f16 MFMA x2 -> planar dx ---
// Block (b, cd, half) covers mlp rows hp in [8cd+4*half, +4); wave wv owns
// ONE row; chunks of 16 pixels wp = u + 8m (m = lane&15). r16 champion body.
// ONE delta: the x-tile + weights are staged via __builtin_amdgcn_global_
// load_lds (width 16) with PRE-SWIZZLED per-lane SOURCE addresses (m173
// pattern): LDS dest is linear (wave-uniform base + lane*16); the granule
// stored at slot s is tg = s^((s>>5)&7) (involution), whose source byte
// offset in its image row is (tg-4)*16. Interior slots [4,516) are swizzle-
// closed; pad slots (0-3, 516-527 per row) and OOB rows pre-zeroed by
// ds_writes (disjoint from DMA slots). Removes 13 staged VGPRs + 13
// ds_writes + select VALU per thread from the stage prologue.
__global__ __launch_bounds__(256, 2) void k_mlp(const float* __restrict__ x,
    float* __restrict__ dxp, const _Float16* __restrict__ W0Fh,
    const _Float16* __restrict__ W0Fl) {
  __shared__ __align__(16) char smem[75264];  // 50688 x-tile | 24576 weights
  const int tid = threadIdx.x;
  const int lane = tid & 63, wv = tid >> 6;
  const int g = lane >> 4, m = lane & 15;
  const int bid = blockIdx.x;
  const int b = bid >> 5, cd = (bid >> 1) & 15, half = bid & 1;
  const int hp0 = cd * 8 + half * 4;
  const float* xb = x + (size_t)b * PLANE;
  float* dpl = dxp + (size_t)(b * 16 + cd) * (HW * HW);

  // ---- stage 6 x rows (hp0-1..hp0+4) zero-padded + swizzled via DMA ----
  {
    const f4 zf = {0.f, 0.f, 0.f, 0.f};
    // pre-zero pad slots: 0-3 and 516-527 per row (granules==slots there)
    if (tid < 96) {
      int row = tid / 16, j = tid % 16;
      int slot = (j < 4) ? j : (512 + j);
      *(f4*)(smem + row * RSTRIDE + slot * 16) = zf;
    }
    // pre-zero OOB rows (only boundary blocks)
    if (hp0 == 0) {
      for (int i = tid; i < 528; i += 256) *(f4*)(smem + i * 16) = zf;
    } else if (hp0 == 124) {
      for (int i = tid; i < 528; i += 256)
        *(f4*)(smem + 5 * RSTRIDE + i * 16) = zf;
    }
    // interior DMA: 48 wave-ops (8 per row), 12 per wave
    #pragma unroll
    for (int k = 0; k < 12; ++k) {
      int op = wv + k * 4;                 // 0..47
      int row = op >> 3;                   // tile row 0..5
      int grow = hp0 - 1 + row;
      if ((unsigned)grow < 128u) {         // wave-uniform skip of OOB rows
        int slot = 4 + (op & 7) * 64 + lane;
        int tg = slot ^ ((slot >> 5) & 7);
        const char* src = (const char*)(xb + (size_t)grow * 2048)
                          + (tg - 4) * 16;
        char* dst = smem + row * RSTRIDE + (4 + (op & 7) * 64) * 16;
        __builtin_amdgcn_global_load_lds(src, dst, 16, 0, 0);
      }
    }
    // weights: W0lo|W1hi|W1lo (24 KB linear) -> smem+50688 via DMA
    #pragma unroll
    for (int k = 0; k < 6; ++k) {
      const char* src = (const char*)W0Fl + k * 4096 + wv * 1024 + lane * 16;
      char* dst = smem + 50688 + k * 4096 + wv * 1024;
      __builtin_amdgcn_global_load_lds(src, dst, 16, 0, 0);
    }
  }
  __syncthreads();   // drains vmcnt (DMA) + lgkmcnt (pre-zero) before reads

  // persistent W0-hi fragments in VGPRs (64 regs)
  h8 w0h[2][8];
  #pragma unroll
  for (int kf = 0; kf < 2; ++kf)
    #pragma unroll
    for (int nf = 0; nf < 8; ++nf)
      w0h[kf][nf] = *(const h8*)(W0Fh + ((kf * 8 + nf) * 64 + lane) * 8);

  const f4 zero4 = {0.f, 0.f, 0.f, 0.f};
  const int chq = (g & 1) * 2;              // granule sub-offset for this g
  const bool lowg = (g < 2);

  const int hp = hp0 + wv;
  const char* xsw = smem + wv * RSTRIDE;    // local row wv = global hp-1
  float* dbase = dpl + (size_t)(hp & 7) * 16 + m + (size_t)g * 4 * 128;

  for (int u = 0; u < 8; ++u) {
    const int wp = u + 8 * m;
    // ---- read 3x3-neighborhood columns from LDS (unconditional) ----
    f4 qA[3][2], qB[3][2], qC[3][2];
    LDQ(wp - 1, qA); LDQ(wp, qB); LDQ(wp + 1, qC);

    // ---- features: center / sobel-dh / sobel-dw for 8 channels ----
    f4 cen0 = qB[1][0], cen1 = qB[1][1];
    f4 sH0 = ((qA[2][0] - qA[0][0]) + 2.f * (qB[2][0] - qB[0][0])
            + (qC[2][0] - qC[0][0])) * 0.125f;
    f4 sH1 = ((qA[2][1] - qA[0][1]) + 2.f * (qB[2][1] - qB[0][1])
            + (qC[2][1] - qC[0][1])) * 0.125f;
    f4 vA0 = qA[0][0] + 2.f * qA[1][0] + qA[2][0];
    f4 vA1 = qA[0][1] + 2.f * qA[1][1] + qA[2][1];
    f4 vC0 = qC[0][0] + 2.f * qC[1][0] + qC[2][0];
    f4 vC1 = qC[0][1] + 2.f * qC[1][1] + qC[2][1];
    f4 sW0 = (vC0 - vA0) * 0.125f;
    f4 sW1 = (vC1 - vA1) * 0.125f;

    f4 f0lo = lowg ? cen0 : sH0, f0hi = lowg ? cen1 : sH1;
    f4 f1lo = lowg ? sW0 : zero4, f1hi = lowg ? sW1 : zero4;

    // ---- split features to hi/lo f16 pairs ----
    union { h8 v; u32 u[4]; } b0h, b0l, b1h, b1l;
    #pragma unroll
    for (int q = 0; q < 4; ++q) {
      float a0 = (q < 2) ? f0lo[2 * q]     : f0hi[2 * q - 4];
      float a1 = (q < 2) ? f0lo[2 * q + 1] : f0hi[2 * q - 3];
      split2(a0, a1, b0h.u[q], b0l.u[q]);
      float c0 = (q < 2) ? f1lo[2 * q]     : f1hi[2 * q - 4];
      float c1 = (q < 2) ? f1lo[2 * q + 1] : f1hi[2 * q - 3];
      split2(c0, c1, b1h.u[q], b1l.u[q]);
    }
    if (g == 3) {                        // bias slot: B[k=63] = 1.0 exactly
      b1h.u[3] = (b1h.u[3] & 0xFFFFu) | 0x3C000000u;
      b1l.u[3] =  b1l.u[3] & 0xFFFFu;
    }

    // ---- fused GEMM1 -> relu/split -> GEMM2, all in-lane; split chains ----
    f4 q0 = zero4, q1 = zero4, q2 = zero4, q3 = zero4;  // GEMM2 per-p chains
    #pragma unroll
    for (int p = 0; p < 4; ++p) {
      f4 aAh = zero4, aAl = zero4, aBh = zero4, aBl = zero4;
      {
        const int nf = 2 * p;
        h8 l0 = *(const h8*)(smem + 50688 + nf * 1024 + lane * 16);  // lo kf0
        h8 l1 = *(const h8*)(smem + 58880 + nf * 1024 + lane * 16);  // lo kf1
        aAh = __builtin_amdgcn_mfma_f32_16x16x32_f16(w0h[0][nf], b0h.v, aAh, 0, 0, 0);
        aAh = __builtin_amdgcn_mfma_f32_16x16x32_f16(w0h[1][nf], b1h.v, aAh, 0, 0, 0);
        aAh = __builtin_amdgcn_mfma_f32_16x16x32_f16(w0h[0][nf], b0l.v, aAh, 0, 0, 0);
        aAh = __builtin_amdgcn_mfma_f32_16x16x32_f16(w0h[1][nf], b1l.v, aAh, 0, 0, 0);
        aAl = __builtin_amdgcn_mfma_f32_16x16x32_f16(l0, b0h.v, aAl, 0, 0, 0);
        aAl = __builtin_amdgcn_mfma_f32_16x16x32_f16(l1, b1h.v, aAl, 0, 0, 0);
      }
      {
        const int nf = 2 * p + 1;
        h8 l0 = *(const h8*)(smem + 50688 + nf * 1024 + lane * 16);
        h8 l1 = *(const h8*)(smem + 58880 + nf * 1024 + lane * 16);
        aBh = __builtin_amdgcn_mfma_f32_16x16x32_f16(w0h[0][nf], b0h.v, aBh, 0, 0, 0);
        aBh = __builtin_amdgcn_mfma_f32_16x16x32_f16(w0h[1][nf], b1h.v, aBh, 0, 0, 0);
        aBh = __builtin_amdgcn_mfma_f32_16x16x32_f16(w0h[0][nf], b0l.v, aBh, 0, 0, 0);
        aBh = __builtin_amdgcn_mfma_f32_16x16x32_f16(w0h[1][nf], b1l.v, aBh, 0, 0, 0);
        aBl = __builtin_amdgcn_mfma_f32_16x16x32_f16(l0, b0h.v, aBl, 0, 0, 0);
        aBl = __builtin_amdgcn_mfma_f32_16x16x32_f16(l1, b1h.v, aBl, 0, 0, 0);
      }
      f4 aA = aAh + aAl;
      f4 aB = aBh + aBl;
      // relu + hi/lo split, element j of B-frag = acc[2p+(j>>2)][j&3]
      union { h8 v; u32 u[4]; } hh, hl;
      split2(fmaxf(aA[0], 0.f), fmaxf(aA[1], 0.f), hh.u[0], hl.u[0]);
      split2(fmaxf(aA[2], 0.f), fmaxf(aA[3], 0.f), hh.u[1], hl.u[1]);
      split2(fmaxf(aB[0], 0.f), fmaxf(aB[1], 0.f), hh.u[2], hl.u[2]);
      split2(fmaxf(aB[2], 0.f), fmaxf(aB[3], 0.f), hh.u[3], hl.u[3]);
      h8 w1hp = *(const h8*)(smem + 67072 + p * 1024 + lane * 16);
      h8 w1lp = *(const h8*)(smem + 71168 + p * 1024 + lane * 16);
      f4 qp = (p == 0) ? q0 : (p == 1) ? q1 : (p == 2) ? q2 : q3;
      qp = __builtin_amdgcn_mfma_f32_16x16x32_f16(w1hp, hh.v, qp, 0, 0, 0);
      qp = __builtin_amdgcn_mfma_f32_16x16x32_f16(w1hp, hl.v, qp, 0, 0, 0);
      qp = __builtin_amdgcn_mfma_f32_16x16x32_f16(w1lp, hh.v, qp, 0, 0, 0);
      if (p == 0) q0 = qp; else if (p == 1) q1 = qp;
      else if (p == 2) q2 = qp; else q3 = qp;
    }
    f4 acc2 = (q0 + q1) + (q2 + q3);

    // ---- store dx plane: lane (g,m) holds cq=4g+r for pixel m ----
    #pragma unroll
    for (int r = 0; r < 4; ++r)
      dbase[(size_t)(u * 16 + r) * 128] = acc2[r];
  }
}

// ---------------- fused residual add + alive masking ----------------------
__global__ __launch_bounds__(256) void k_addlife(const float* __restrict__ xo,
    const float* __restrict__ dxp, float* __restrict__ xn) {
  int p = blockIdx.x * 256 + threadIdx.x;
  int b = p >> 14, rem = p & 16383;
  int h = rem >> 7, w = rem & 127;
  const float* xop = xo + (size_t)p * 16;
  const float* dplane = dxp + (size_t)b * 16 * 16384;
  f4 xv[4];
  #pragma unroll
  for (int i = 0; i < 4; ++i) xv[i] = *(const f4*)(xop + i * 4);
  float dxv[16];
  #pragma unroll
  for (int c = 0; c < 16; ++c) dxv[c] = dplane[c * 16384 + rem];
  f4 nv[4];
  #pragma unroll
  for (int i = 0; i < 4; ++i) {
    nv[i][0] = xv[i][0] + dxv[i * 4 + 0];
    nv[i][1] = xv[i][1] + dxv[i * 4 + 1];
    nv[i][2] = xv[i][2] + dxv[i * 4 + 2];
    nv[i][3] = xv[i][3] + dxv[i * 4 + 3];
  }
  float pre = -1e30f, post = -1e30f;
  const float* xb3 = xo + (size_t)b * 16384 * 16 + 3;
  const float* d3p = dplane + 3 * 16384;
  #pragma unroll
  for (int dh = -1; dh <= 1; ++dh)
    #pragma unroll
    for (int dw = -1; dw <= 1; ++dw) {
      int hh = h + dh, ww = w + dw;
      bool v = ((unsigned)hh < 128u) && ((unsigned)ww < 128u);
      int rp = hh * 128 + ww;
      float x3 = v ? xb3[(size_t)rp * 16] : -1e30f;
      float d3 = v ? d3p[rp] : 0.f;
      pre = fmaxf(pre, x3);
      post = fmaxf(post, v ? (x3 + d3) : -1e30f);
    }
  bool life = (pre > 0.1f) && (post > 0.1f);
  float* out = xn + (size_t)p * 16;
  f4 z = {0.f, 0.f, 0.f, 0.f};
  #pragma unroll
  for (int i = 0; i < 4; ++i) *(f4*)(out + i * 4) = life ? nv[i] : z;
}

extern "C" void kernel_launch(void* const* d_in, const int* in_sizes, int n_in,
                              void* d_out, int out_size, void* d_ws, size_t ws_size,
                              hipStream_t stream) {
  const float* x0 = (const float*)d_in[0];
  const float* W0 = (const float*)d_in[1];
  const float* b0 = (const float*)d_in[2];
  const float* W1 = (const float*)d_in[3];

  float*    A    = (float*)d_ws;                                  // 32 MB x ping
  float*    dxp  = (float*)((char*)d_ws + ((size_t)32 << 20));    // 32 MB dx
  _Float16* W0Fh = (_Float16*)((char*)d_ws + ((size_t)64 << 20)); // 16 KB
  _Float16* W0Fl = W0Fh + 8192;   // 16 KB  (W0Fh|W0Fl|W1Fh|W1Fl contig 40 KB)
  _Float16* W1Fh = W0Fl + 8192;   // 4 KB
  _Float16* W1Fl = W1Fh + 2048;   // 4 KB
  float*    Bo   = (float*)d_out;

  k_wprep<<<40, 256, 0, stream>>>(W0, W1, b0, W0Fh, W0Fl, W1Fh, W1Fl);

  const float* xcur = x0;
  for (int s = 1; s <= 8; ++s) {
    k_mlp<<<1024, 256, 0, stream>>>(xcur, dxp, W0Fh, W0Fl);
    float* xnext = (s & 1) ? A : Bo;        // step 8 lands in d_out
    k_addlife<<<2048, 256, 0, stream>>>(xcur, dxp, xnext);
    xcur = xnext;
  }
}